// Round 9
// baseline (5982.910 us; speedup 1.0000x reference)
//
#include <hip/hip_runtime.h>
#include <math.h>

constexpr int H   = 512;
constexpr int B   = 512;
constexpr int T   = 256;
constexpr int F   = 8;
constexpr int HOR = 24;

typedef _Float16 f16;
typedef _Float16 f16x8 __attribute__((ext_vector_type(8)));
typedef float    f32x4 __attribute__((ext_vector_type(4)));

__device__ __forceinline__ float sigm(float x) { return 1.0f / (1.0f + expf(-x)); }

// ---------------------------------------------------------------------------
// LLC-coherent (cross-XCD) path: sc0 sc1 bypasses L1/L2; h tiles + flags live
// in the Infinity Cache. Weights / x / biases / c stay on the cached path.
// 16 strided 16B loads: two 16B chunks per 128B K-chunk (offs k*128+{0,16}).
#define LLC_LOAD16S(base, r) \
  asm volatile( \
    "global_load_dwordx4 %0,  %16, off sc0 sc1\n\t" \
    "global_load_dwordx4 %1,  %16, off offset:16 sc0 sc1\n\t" \
    "global_load_dwordx4 %2,  %16, off offset:128 sc0 sc1\n\t" \
    "global_load_dwordx4 %3,  %16, off offset:144 sc0 sc1\n\t" \
    "global_load_dwordx4 %4,  %16, off offset:256 sc0 sc1\n\t" \
    "global_load_dwordx4 %5,  %16, off offset:272 sc0 sc1\n\t" \
    "global_load_dwordx4 %6,  %16, off offset:384 sc0 sc1\n\t" \
    "global_load_dwordx4 %7,  %16, off offset:400 sc0 sc1\n\t" \
    "global_load_dwordx4 %8,  %16, off offset:512 sc0 sc1\n\t" \
    "global_load_dwordx4 %9,  %16, off offset:528 sc0 sc1\n\t" \
    "global_load_dwordx4 %10, %16, off offset:640 sc0 sc1\n\t" \
    "global_load_dwordx4 %11, %16, off offset:656 sc0 sc1\n\t" \
    "global_load_dwordx4 %12, %16, off offset:768 sc0 sc1\n\t" \
    "global_load_dwordx4 %13, %16, off offset:784 sc0 sc1\n\t" \
    "global_load_dwordx4 %14, %16, off offset:896 sc0 sc1\n\t" \
    "global_load_dwordx4 %15, %16, off offset:912 sc0 sc1" \
    : "=v"(r[0]), "=v"(r[1]), "=v"(r[2]), "=v"(r[3]), \
      "=v"(r[4]), "=v"(r[5]), "=v"(r[6]), "=v"(r[7]), \
      "=v"(r[8]), "=v"(r[9]), "=v"(r[10]), "=v"(r[11]), \
      "=v"(r[12]), "=v"(r[13]), "=v"(r[14]), "=v"(r[15]) \
    : "v"(base))

// 16 contiguous 16B loads (256B run) for the pred head.
#define LLC_LOAD16C(base, r) \
  asm volatile( \
    "global_load_dwordx4 %0,  %16, off sc0 sc1\n\t" \
    "global_load_dwordx4 %1,  %16, off offset:16 sc0 sc1\n\t" \
    "global_load_dwordx4 %2,  %16, off offset:32 sc0 sc1\n\t" \
    "global_load_dwordx4 %3,  %16, off offset:48 sc0 sc1\n\t" \
    "global_load_dwordx4 %4,  %16, off offset:64 sc0 sc1\n\t" \
    "global_load_dwordx4 %5,  %16, off offset:80 sc0 sc1\n\t" \
    "global_load_dwordx4 %6,  %16, off offset:96 sc0 sc1\n\t" \
    "global_load_dwordx4 %7,  %16, off offset:112 sc0 sc1\n\t" \
    "global_load_dwordx4 %8,  %16, off offset:128 sc0 sc1\n\t" \
    "global_load_dwordx4 %9,  %16, off offset:144 sc0 sc1\n\t" \
    "global_load_dwordx4 %10, %16, off offset:160 sc0 sc1\n\t" \
    "global_load_dwordx4 %11, %16, off offset:176 sc0 sc1\n\t" \
    "global_load_dwordx4 %12, %16, off offset:192 sc0 sc1\n\t" \
    "global_load_dwordx4 %13, %16, off offset:208 sc0 sc1\n\t" \
    "global_load_dwordx4 %14, %16, off offset:224 sc0 sc1\n\t" \
    "global_load_dwordx4 %15, %16, off offset:240 sc0 sc1" \
    : "=v"(r[0]), "=v"(r[1]), "=v"(r[2]), "=v"(r[3]), \
      "=v"(r[4]), "=v"(r[5]), "=v"(r[6]), "=v"(r[7]), \
      "=v"(r[8]), "=v"(r[9]), "=v"(r[10]), "=v"(r[11]), \
      "=v"(r[12]), "=v"(r[13]), "=v"(r[14]), "=v"(r[15]) \
    : "v"(base))

// Drain vmcnt and ORDER all subsequent uses of r[] after it ("+v" ties).
#define VWAIT16(r) \
  asm volatile("s_waitcnt vmcnt(0)" \
    : "+v"(r[0]), "+v"(r[1]), "+v"(r[2]), "+v"(r[3]), \
      "+v"(r[4]), "+v"(r[5]), "+v"(r[6]), "+v"(r[7]), \
      "+v"(r[8]), "+v"(r[9]), "+v"(r[10]), "+v"(r[11]), \
      "+v"(r[12]), "+v"(r[13]), "+v"(r[14]), "+v"(r[15]) :: "memory")

// h-element write-through store (2B).
#define LLC_STORE_SHORT(p, v) \
  asm volatile("global_store_short %0, %1, off sc0 sc1" :: "v"(p), "v"(v) : "memory")

// Release-ish flag store: all prior stores reach the LLC before the flag.
#define FLAG_STORE(p, v) \
  asm volatile("s_waitcnt vmcnt(0)\n\t" \
               "global_store_dword %0, %1, off sc0 sc1" :: "v"(p), "v"(v) : "memory")
#define FLAG_STORE_NW(p, v) \
  asm volatile("global_store_dword %0, %1, off sc0 sc1" :: "v"(p), "v"(v) : "memory")

// ---------------------------------------------------------------------------
// Weight convert: fp32 [4H][H] gate-major rows (row = g*H + jh) -> fp16
// [2048][512] permuted rows n' = jh*4 + g. grid (512, 6).
__global__ __launch_bounds__(256)
void wconv_k(const float* __restrict__ s0, f16* __restrict__ d0,
             const float* __restrict__ s1, f16* __restrict__ d1,
             const float* __restrict__ s2, f16* __restrict__ d2,
             const float* __restrict__ s3, f16* __restrict__ d3,
             const float* __restrict__ s4, f16* __restrict__ d4,
             const float* __restrict__ s5, f16* __restrict__ d5)
{
    const float* src; f16* dst;
    switch (blockIdx.y) {
        case 0:  src = s0; dst = d0; break;
        case 1:  src = s1; dst = d1; break;
        case 2:  src = s2; dst = d2; break;
        case 3:  src = s3; dst = d3; break;
        case 4:  src = s4; dst = d4; break;
        default: src = s5; dst = d5; break;
    }
    int idx = (blockIdx.x * 256 + threadIdx.x) * 8;
    int np  = idx >> 9;
    int k   = idx & 511;
    int jh  = np >> 2, g = np & 3;
    const float* sp = src + (size_t)(g * H + jh) * H + k;
    f16 tmp[8];
    #pragma unroll
    for (int j = 0; j < 8; ++j) tmp[j] = (f16)sp[j];
    *(f16x8*)(dst + idx) = *(const f16x8*)tmp;
}

// ---------------------------------------------------------------------------
// Poll 16 per-producer epoch flags with LLC loads (no fences, no L2 inv).
__device__ __forceinline__ void wait_group(const int* f, int target)
{
    if (threadIdx.x < 64) {
        const int* p = f + (threadIdx.x & 15);
        bool ok;
        do {
            int v = target;
            if (threadIdx.x < 16)
                asm volatile("global_load_dword %0, %1, off sc0 sc1\n\t"
                             "s_waitcnt vmcnt(0)"
                             : "=v"(v) : "v"(p) : "memory");
            ok = __all(v >= target);
            if (!ok) __builtin_amdgcn_s_sleep(1);
        } while (!ok);
    }
    __syncthreads();
}

// ---------------------------------------------------------------------------
struct WChunk { f16x8 w0, w1; };

__device__ __forceinline__ WChunk loadW(int kt, const f16* __restrict__ W0,
                                        const f16* __restrict__ W1,
                                        int n0, int srow, int sch)
{
    const f16* Wp = (kt < 8) ? W0 : W1;
    const int  ko = ((kt < 8) ? kt : kt - 8) * 64;
    const f16* wp = Wp + (size_t)(n0 + srow) * H + ko + sch * 16;
    WChunk c;
    c.w0 = *(const f16x8*)wp;
    c.w1 = *(const f16x8*)(wp + 8);
    return c;
}

// Fused LSTM cell, 64 b-rows x TWO adjacent 64-n' tiles (nt = nt2*2 + p),
// K = NKT*64 (NKT = 0, 8 or 16). Two sequential passes share one set of
// A registers (LLC-loaded once) -> halves LLC A traffic and flag fan-in.
// Per-pass core (wave layout, LDS addressing, epilogue) is the R4-R7
// validated 256-thread 64x64 code, unmodified.
// xmode: 0 none; 1 enc0 F=8 fp32 x-path; 2 scalar xptr[b*xstride]; 3 pred_s.
template<int NKT>
__device__ __forceinline__ void cell_body(int bt, int nt2, char* smem,
    const f16* __restrict__ A0, const f16* __restrict__ A1,
    const f16* __restrict__ W0, const f16* __restrict__ W1,
    const float* __restrict__ bih, const float* __restrict__ bhh,
    int xmode, const float* __restrict__ xptr, int xstride,
    const float* __restrict__ xw, const float* __restrict__ pred_s,
    float* __restrict__ cst, f16* __restrict__ hout)
{
    constexpr int ABUF = 64 * 72;                  // halfs per buffer slot
    f16*   As = (f16*)smem;                        // [2][64][72]
    f16*   Ws = (f16*)smem + 2 * ABUF;             // [2][64][72]
    float* zs = (float*)smem;                      // overlay after each K-loop

    const int tid  = threadIdx.x;
    const int lane = tid & 63;
    const int wv   = tid >> 6;
    const int wm   = wv & 1;
    const int wn   = wv >> 1;
    const int r    = lane & 15;
    const int g4   = lane >> 4;
    const int b0   = bt * 64;
    const int srow = tid >> 2, sch = tid & 3;

    // A (h state) loaded once into registers; reused by both n-tile passes.
    f16x8 ar[16];
    f16x8 br[16];
    if constexpr (NKT > 0) {
        const f16* ap = A0 + (size_t)(b0 + srow) * H + sch * 16;
        LLC_LOAD16S(ap, ar);
        if constexpr (NKT == 16) {
            const f16* bp = A1 + (size_t)(b0 + srow) * H + sch * 16;
            LLC_LOAD16S(bp, br);
        }
        VWAIT16(ar);           // drains all outstanding (incl. br group)
    }

    #pragma unroll
    for (int p = 0; p < 2; ++p) {
        const int nt  = nt2 * 2 + p;
        const int n0  = nt * 64;
        const int jh0 = nt * 16;

        f32x4 acc[2][2] = {};

        if constexpr (NKT > 0) {
            WChunk wcur = loadW(0, W0, W1, n0, srow, sch);
            #pragma unroll
            for (int kt = 0; kt < NKT; ++kt) {
                f16* Ab = As + (kt & 1) * ABUF;
                f16* Wb = Ws + (kt & 1) * ABUF;
                f16x8 a0v = (kt < 8) ? ar[kt * 2]     : br[(kt - 8) * 2];
                f16x8 a1v = (kt < 8) ? ar[kt * 2 + 1] : br[(kt - 8) * 2 + 1];
                *(f16x8*)(Ab + srow * 72 + sch * 16)     = a0v;
                *(f16x8*)(Ab + srow * 72 + sch * 16 + 8) = a1v;
                *(f16x8*)(Wb + srow * 72 + sch * 16)     = wcur.w0;
                *(f16x8*)(Wb + srow * 72 + sch * 16 + 8) = wcur.w1;
                __syncthreads();

                WChunk wnxt = wcur;
                if (kt + 1 < NKT) wnxt = loadW(kt + 1, W0, W1, n0, srow, sch);

                #pragma unroll
                for (int sub = 0; sub < 2; ++sub) {
                    f16x8 bf0 = *(const f16x8*)(Wb + (wn * 32 + r)      * 72 + sub * 32 + g4 * 8);
                    f16x8 bf1 = *(const f16x8*)(Wb + (wn * 32 + 16 + r) * 72 + sub * 32 + g4 * 8);
                    f16x8 af0 = *(const f16x8*)(Ab + (wm * 32 + r)      * 72 + sub * 32 + g4 * 8);
                    f16x8 af1 = *(const f16x8*)(Ab + (wm * 32 + 16 + r) * 72 + sub * 32 + g4 * 8);
                    acc[0][0] = __builtin_amdgcn_mfma_f32_16x16x32_f16(af0, bf0, acc[0][0], 0, 0, 0);
                    acc[0][1] = __builtin_amdgcn_mfma_f32_16x16x32_f16(af0, bf1, acc[0][1], 0, 0, 0);
                    acc[1][0] = __builtin_amdgcn_mfma_f32_16x16x32_f16(af1, bf0, acc[1][0], 0, 0, 0);
                    acc[1][1] = __builtin_amdgcn_mfma_f32_16x16x32_f16(af1, bf1, acc[1][1], 0, 0, 0);
                }
                wcur = wnxt;
            }
        }

        __syncthreads();   // last frag reads drained before zs overlay
        #pragma unroll
        for (int fm = 0; fm < 2; ++fm)
            #pragma unroll
            for (int fn = 0; fn < 2; ++fn)
                #pragma unroll
                for (int j = 0; j < 4; ++j)
                    zs[(wm * 32 + fm * 16 + g4 * 4 + j) * 68 +
                       (wn * 32 + fn * 16 + r)] = acc[fm][fn][j];
        __syncthreads();

        // epilogue: thread -> (4 b-rows, 1 jh); gates = 4 consecutive n'.
        const int jl = tid & 15;
        const int bq = tid >> 4;
        const int jh = jh0 + jl;

        float bsum[4];
        #pragma unroll
        for (int g = 0; g < 4; ++g) bsum[g] = bih[g * H + jh] + bhh[g * H + jh];

        #pragma unroll
        for (int bb = 0; bb < 4; ++bb) {
            const int bl = bq * 4 + bb;
            const int b  = b0 + bl;
            float4 z = *(const float4*)(zs + bl * 68 + jl * 4);
            float zi = z.x + bsum[0];
            float zf = z.y + bsum[1];
            float zg = z.z + bsum[2];
            float zo = z.w + bsum[3];
            if (xmode == 1) {
                const float* xr = xptr + (size_t)b * xstride;
                #pragma unroll
                for (int k = 0; k < F; ++k) {
                    float xv = xr[k];
                    zi += xv * xw[(0 * H + jh) * F + k];
                    zf += xv * xw[(1 * H + jh) * F + k];
                    zg += xv * xw[(2 * H + jh) * F + k];
                    zo += xv * xw[(3 * H + jh) * F + k];
                }
            } else if (xmode == 2 || xmode == 3) {
                float xv = (xmode == 2) ? xptr[(size_t)b * xstride] : pred_s[bl];
                zi += xv * xw[0 * H + jh];
                zf += xv * xw[1 * H + jh];
                zg += xv * xw[2 * H + jh];
                zo += xv * xw[3 * H + jh];
            }
            size_t idx = (size_t)b * H + jh;
            float cold = cst[idx];                  // c is block-private: cached path
            float cn = sigm(zf) * cold + sigm(zi) * tanhf(zg);
            cst[idx] = cn;
            union { f16 h; unsigned short u; } cv;
            cv.h = (f16)(sigm(zo) * tanhf(cn));
            LLC_STORE_SHORT(hout + idx, (int)cv.u); // h crosses blocks: LLC path
        }
        __syncthreads();   // zs reads done before next pass restages As/Ws
    }
}

// ---------------------------------------------------------------------------
// pred for 64 rows of this bt: pred_s[row] = h1row . outW + outb.
// All 16 nt2 blocks compute redundantly; only nt2==0 writes d_out[., oidx].
__device__ __forceinline__ void compute_pred(int bt, int nt2,
                             const f16* __restrict__ h1src,
                             const float* __restrict__ outW,
                             const float* __restrict__ outb,
                             float* pred_s, float* __restrict__ dout, int oidx)
{
    const int row = threadIdx.x >> 2;
    const int q   = threadIdx.x & 3;
    const int b   = bt * 64 + row;
    f16x8 hr[16];
    const f16* hp = h1src + (size_t)b * H + q * 128;
    LLC_LOAD16C(hp, hr);
    VWAIT16(hr);
    float s = 0.f;
    #pragma unroll
    for (int k8 = 0; k8 < 16; ++k8) {
        const float* wr = outW + q * 128 + k8 * 8;
        #pragma unroll
        for (int j = 0; j < 8; ++j) s += (float)hr[k8][j] * wr[j];
    }
    s += __shfl_down(s, 2);
    s += __shfl_down(s, 1);
    if (q == 0) {
        float p = s + outb[0];
        pred_s[row] = p;
        if (nt2 == 0) dout[(size_t)b * HOR + oidx] = p;
    }
    __syncthreads();
}

// ---------------------------------------------------------------------------
struct PArgs {
    const f16 *wh0, *wih1, *whh1, *dwh0, *dwih1, *dwhh1;
    const float *x;
    const float *ebih0, *ebhh0, *ebih1, *ebhh1;
    const float *dbih0, *dbhh0, *dbih1, *dbhh1;
    const float *eWih0, *dWih0, *outW, *outb;
    f16 *h0ring, *h1ping, *h0dping, *h1dping;
    float *c0, *c1, *dout;
    int *f0, *f1, *fc0, *f0d, *f1d;   // epoch flags, [8 bt][16 nt2] each
};

// Persistent kernel: 256 blocks x 256 threads (37.1KB LDS; co-resident).
// bid bits: [2:0]=nt2&7 (XCD under round-robin bid%8), [3]=role, [6:4]=bt,
// [7]=nt2>>3. Each block owns TWO adjacent n'-tiles (nt = nt2*2+{0,1}).
// Per XCD: 4 n'-tiles/layer => W working set ~1.5MB < 4MB L2 -> W L2-resident
// (locality heuristic; correctness from the LLC-coherent sc0sc1 path).
__global__ __launch_bounds__(256, 2)
void persist_k(PArgs a)
{
    __shared__ __align__(16) char smem[37120];
    float* pred_s = (float*)(smem + 36864);
    const size_t BH = (size_t)B * H;
    const int bid  = blockIdx.x;
    const int role = (bid >> 3) & 1;
    const int bt   = (bid >> 4) & 7;
    const int nt2  = (bid & 7) | (((bid >> 7) & 1) << 3);   // 0..15
    int* const myf0  = a.f0  + bt * 16;
    int* const myf1  = a.f1  + bt * 16;
    int* const myfc0 = a.fc0 + bt * 16;
    int* const myf0d = a.f0d + bt * 16;
    int* const myf1d = a.f1d + bt * 16;

    if (role == 0) {
        // ---- encoder layer0: h0(t) = cell(x(t), h0(t-1)) ----
        for (int t = 0; t < T; ++t) {
            if (t >= 1) wait_group(myf0, t);        // h0(t-1) ready (all 16 tiles)
            if (t >= 4) wait_group(myfc0, t - 3);   // ring slot consumed by layer1
            const f16* hp = a.h0ring + (size_t)((t + 3) & 3) * BH;
            f16* ho = a.h0ring + (size_t)(t & 3) * BH;
            if (t == 0)
                cell_body<0>(bt, nt2, smem, hp, hp, a.wh0, a.wh0, a.ebih0, a.ebhh0,
                             1, a.x + (size_t)t * F, T * F, a.eWih0, nullptr, a.c0, ho);
            else
                cell_body<8>(bt, nt2, smem, hp, hp, a.wh0, a.wh0, a.ebih0, a.ebhh0,
                             1, a.x + (size_t)t * F, T * F, a.eWih0, nullptr, a.c0, ho);
            __syncthreads();
            if (threadIdx.x == 0) FLAG_STORE(myf0 + nt2, t + 1);
        }
        // ---- decoder layer0 (+ pred head) ----
        for (int td = 0; td <= HOR; ++td) {
            if (td == 0) {
                wait_group(myf0, T);                // own group enc done
            } else {
                wait_group(myf1d, td);              // h1d(td-1) ready
                compute_pred(bt, nt2, a.h1dping + (size_t)((td + 1) & 1) * BH,
                             a.outW, a.outb, pred_s, a.dout, td - 1);
            }
            if (td == HOR) break;
            if (td >= 1) wait_group(myf0d, td);     // h0d(td-1) ready
            const f16* hp = (td == 0) ? a.h0ring + (size_t)3 * BH
                                      : a.h0dping + (size_t)((td + 1) & 1) * BH;
            if (td == 0)
                cell_body<8>(bt, nt2, smem, hp, hp, a.dwh0, a.dwh0, a.dbih0, a.dbhh0,
                             2, a.x + (size_t)(T - 1) * F, T * F, a.dWih0, nullptr,
                             a.c0, a.h0dping);
            else
                cell_body<8>(bt, nt2, smem, hp, hp, a.dwh0, a.dwh0, a.dbih0, a.dbhh0,
                             3, nullptr, 0, a.dWih0, pred_s,
                             a.c0, a.h0dping + (size_t)(td & 1) * BH);
            __syncthreads();
            if (threadIdx.x == 0) FLAG_STORE(myf0d + nt2, td + 1);
        }
    } else {
        // ---- encoder layer1: h1(t) = cell([h0(t)|h1(t-1)]) ----
        for (int t = 0; t < T; ++t) {
            wait_group(myf0, t + 1);                // h0(t) ready
            if (t >= 1) wait_group(myf1, t);        // h1(t-1) ready
            const f16* a0 = a.h0ring + (size_t)(t & 3) * BH;
            const f16* a1 = a.h1ping + (size_t)((t + 1) & 1) * BH;
            f16* ho = a.h1ping + (size_t)(t & 1) * BH;
            if (t == 0)
                cell_body<8>(bt, nt2, smem, a0, a0, a.wih1, a.wih1, a.ebih1, a.ebhh1,
                             0, nullptr, 0, nullptr, nullptr, a.c1, ho);
            else
                cell_body<16>(bt, nt2, smem, a0, a1, a.wih1, a.whh1, a.ebih1, a.ebhh1,
                              0, nullptr, 0, nullptr, nullptr, a.c1, ho);
            __syncthreads();
            if (threadIdx.x == 0) {
                FLAG_STORE(myf1 + nt2, t + 1);      // vmcnt(0) inside orders h stores
                FLAG_STORE_NW(myfc0 + nt2, t + 1);  // ring-consumption signal
            }
        }
        // ---- decoder layer1 ----
        for (int td = 0; td < HOR; ++td) {
            wait_group(myf0d, td + 1);              // h0d(td) ready
            const f16* a1;
            if (td == 0) { wait_group(myf1, T);   a1 = a.h1ping + BH; }
            else         { wait_group(myf1d, td); a1 = a.h1dping + (size_t)((td + 1) & 1) * BH; }
            cell_body<16>(bt, nt2, smem, a.h0dping + (size_t)(td & 1) * BH, a1,
                          a.dwih1, a.dwhh1, a.dbih1, a.dbhh1,
                          0, nullptr, 0, nullptr, nullptr,
                          a.c1, a.h1dping + (size_t)(td & 1) * BH);
            __syncthreads();
            if (threadIdx.x == 0) FLAG_STORE(myf1d + nt2, td + 1);
        }
    }
}

// ---------------------------------------------------------------------------
extern "C" void kernel_launch(void* const* d_in, const int* in_sizes, int n_in,
                              void* d_out, int out_size, void* d_ws, size_t ws_size,
                              hipStream_t stream)
{
    const float* x     = (const float*)d_in[0];
    const float* eWih0 = (const float*)d_in[1];
    const float* eWhh0 = (const float*)d_in[2];
    const float* ebih0 = (const float*)d_in[3];
    const float* ebhh0 = (const float*)d_in[4];
    const float* eWih1 = (const float*)d_in[5];
    const float* eWhh1 = (const float*)d_in[6];
    const float* ebih1 = (const float*)d_in[7];
    const float* ebhh1 = (const float*)d_in[8];
    const float* dWih0 = (const float*)d_in[9];
    const float* dWhh0 = (const float*)d_in[10];
    const float* dbih0 = (const float*)d_in[11];
    const float* dbhh0 = (const float*)d_in[12];
    const float* dWih1 = (const float*)d_in[13];
    const float* dWhh1 = (const float*)d_in[14];
    const float* dbih1 = (const float*)d_in[15];
    const float* dbhh1 = (const float*)d_in[16];
    const float* outW  = (const float*)d_in[17];
    const float* outb  = (const float*)d_in[18];

    const size_t WSZ = (size_t)4 * H * H;   // halfs per converted weight
    const size_t BH  = (size_t)B * H;

    char* wsb = (char*)d_ws;
    size_t off = 0;
    f16* wh[6];
    for (int i = 0; i < 6; ++i) { wh[i] = (f16*)(wsb + off); off += WSZ * sizeof(f16); }
    f16* h0ring  = (f16*)(wsb + off); off += 4 * BH * sizeof(f16);
    f16* h1ping  = (f16*)(wsb + off); off += 2 * BH * sizeof(f16);
    f16* h0dping = (f16*)(wsb + off); off += 2 * BH * sizeof(f16);
    f16* h1dping = (f16*)(wsb + off); off += 2 * BH * sizeof(f16);
    float* c0    = (float*)(wsb + off); off += BH * sizeof(float);
    float* c1    = (float*)(wsb + off); off += BH * sizeof(float);
    size_t coff  = off;
    int* f0      = (int*)(wsb + off); off += 8 * 16 * sizeof(int);
    int* f1      = (int*)(wsb + off); off += 8 * 16 * sizeof(int);
    int* fc0     = (int*)(wsb + off); off += 8 * 16 * sizeof(int);
    int* f0d     = (int*)(wsb + off); off += 8 * 16 * sizeof(int);
    int* f1d     = (int*)(wsb + off); off += 8 * 16 * sizeof(int);
    size_t cbytes = off - coff;

    // fp16 weight conversion (permuted layout) + state/flag init, every call
    wconv_k<<<dim3(512, 6), 256, 0, stream>>>(eWhh0, wh[0], eWih1, wh[1], eWhh1, wh[2],
                                              dWhh0, wh[3], dWih1, wh[4], dWhh1, wh[5]);
    hipMemsetAsync(c0, 0, BH * sizeof(float), stream);
    hipMemsetAsync(c1, 0, BH * sizeof(float), stream);
    hipMemsetAsync((char*)wsb + coff, 0, cbytes, stream);

    PArgs a;
    a.wh0 = wh[0]; a.wih1 = wh[1]; a.whh1 = wh[2];
    a.dwh0 = wh[3]; a.dwih1 = wh[4]; a.dwhh1 = wh[5];
    a.x = x;
    a.ebih0 = ebih0; a.ebhh0 = ebhh0; a.ebih1 = ebih1; a.ebhh1 = ebhh1;
    a.dbih0 = dbih0; a.dbhh0 = dbhh0; a.dbih1 = dbih1; a.dbhh1 = dbhh1;
    a.eWih0 = eWih0; a.dWih0 = dWih0; a.outW = outW; a.outb = outb;
    a.h0ring = h0ring; a.h1ping = h1ping; a.h0dping = h0dping; a.h1dping = h1dping;
    a.c0 = c0; a.c1 = c1; a.dout = (float*)d_out;
    a.f0 = f0; a.f1 = f1; a.fc0 = fc0; a.f0d = f0d; a.f1d = f1d;

    persist_k<<<dim3(256), dim3(256), 0, stream>>>(a);
}

// Round 10
// 4519.228 us; speedup vs baseline: 1.3239x; 1.3239x over previous
//
#include <hip/hip_runtime.h>
#include <math.h>

constexpr int H   = 512;
constexpr int B   = 512;
constexpr int T   = 256;
constexpr int F   = 8;
constexpr int HOR = 24;

typedef _Float16 f16;
typedef _Float16 f16x8 __attribute__((ext_vector_type(8)));
typedef float    f32x4 __attribute__((ext_vector_type(4)));

__device__ __forceinline__ float sigm(float x) { return 1.0f / (1.0f + expf(-x)); }

// ---------------------------------------------------------------------------
// LLC-coherent (cross-XCD / cross-block) path: sc0 sc1 bypasses L1/L2. Used
// for h tiles + flags (anything read by other blocks within a kernel).
// Weights / x / biases / c use the normal cached path. Data crossing kernel
// boundaries is coherent either way (L2 inv at dispatch, WB at retire).
#define LLC_LOAD16S(base, r) \
  asm volatile( \
    "global_load_dwordx4 %0,  %16, off sc0 sc1\n\t" \
    "global_load_dwordx4 %1,  %16, off offset:16 sc0 sc1\n\t" \
    "global_load_dwordx4 %2,  %16, off offset:128 sc0 sc1\n\t" \
    "global_load_dwordx4 %3,  %16, off offset:144 sc0 sc1\n\t" \
    "global_load_dwordx4 %4,  %16, off offset:256 sc0 sc1\n\t" \
    "global_load_dwordx4 %5,  %16, off offset:272 sc0 sc1\n\t" \
    "global_load_dwordx4 %6,  %16, off offset:384 sc0 sc1\n\t" \
    "global_load_dwordx4 %7,  %16, off offset:400 sc0 sc1\n\t" \
    "global_load_dwordx4 %8,  %16, off offset:512 sc0 sc1\n\t" \
    "global_load_dwordx4 %9,  %16, off offset:528 sc0 sc1\n\t" \
    "global_load_dwordx4 %10, %16, off offset:640 sc0 sc1\n\t" \
    "global_load_dwordx4 %11, %16, off offset:656 sc0 sc1\n\t" \
    "global_load_dwordx4 %12, %16, off offset:768 sc0 sc1\n\t" \
    "global_load_dwordx4 %13, %16, off offset:784 sc0 sc1\n\t" \
    "global_load_dwordx4 %14, %16, off offset:896 sc0 sc1\n\t" \
    "global_load_dwordx4 %15, %16, off offset:912 sc0 sc1" \
    : "=v"(r[0]), "=v"(r[1]), "=v"(r[2]), "=v"(r[3]), \
      "=v"(r[4]), "=v"(r[5]), "=v"(r[6]), "=v"(r[7]), \
      "=v"(r[8]), "=v"(r[9]), "=v"(r[10]), "=v"(r[11]), \
      "=v"(r[12]), "=v"(r[13]), "=v"(r[14]), "=v"(r[15]) \
    : "v"(base))

#define VWAIT16(r) \
  asm volatile("s_waitcnt vmcnt(0)" \
    : "+v"(r[0]), "+v"(r[1]), "+v"(r[2]), "+v"(r[3]), \
      "+v"(r[4]), "+v"(r[5]), "+v"(r[6]), "+v"(r[7]), \
      "+v"(r[8]), "+v"(r[9]), "+v"(r[10]), "+v"(r[11]), \
      "+v"(r[12]), "+v"(r[13]), "+v"(r[14]), "+v"(r[15]) :: "memory")

// Coalesced 16B h-store (write-through, cross-block visible).
#define LLC_STORE_DWX4(p, v) \
  asm volatile("global_store_dwordx4 %0, %1, off sc0 sc1" :: "v"(p), "v"(v) : "memory")

// Release-ish flag store: caller must be post-__syncthreads (per-wave vmcnt
// drained by the barrier), so prior h stores are at the LLC before the flag.
#define FLAG_STORE(p, v) \
  asm volatile("s_waitcnt vmcnt(0)\n\t" \
               "global_store_dword %0, %1, off sc0 sc1" :: "v"(p), "v"(v) : "memory")

// ---------------------------------------------------------------------------
// Weight convert: fp32 [4H][H] gate-major rows (row = g*H + jh) -> fp16
// [2048][512] permuted rows n' = jh*4 + g. grid (512, 6).
__global__ __launch_bounds__(256)
void wconv_k(const float* __restrict__ s0, f16* __restrict__ d0,
             const float* __restrict__ s1, f16* __restrict__ d1,
             const float* __restrict__ s2, f16* __restrict__ d2,
             const float* __restrict__ s3, f16* __restrict__ d3,
             const float* __restrict__ s4, f16* __restrict__ d4,
             const float* __restrict__ s5, f16* __restrict__ d5)
{
    const float* src; f16* dst;
    switch (blockIdx.y) {
        case 0:  src = s0; dst = d0; break;
        case 1:  src = s1; dst = d1; break;
        case 2:  src = s2; dst = d2; break;
        case 3:  src = s3; dst = d3; break;
        case 4:  src = s4; dst = d4; break;
        default: src = s5; dst = d5; break;
    }
    int idx = (blockIdx.x * 256 + threadIdx.x) * 8;
    int np  = idx >> 9;
    int k   = idx & 511;
    int jh  = np >> 2, g = np & 3;
    const float* sp = src + (size_t)(g * H + jh) * H + k;
    f16 tmp[8];
    #pragma unroll
    for (int j = 0; j < 8; ++j) tmp[j] = (f16)sp[j];
    *(f16x8*)(dst + idx) = *(const f16x8*)tmp;
}

// ---------------------------------------------------------------------------
// Poll 32 per-producer epoch flags with LLC loads (no fences, no L2 inv).
__device__ __forceinline__ void wait_group(const int* f, int target)
{
    if (threadIdx.x < 64) {
        const int* p = f + (threadIdx.x & 31);
        bool ok;
        do {
            int v = target;
            if (threadIdx.x < 32)
                asm volatile("global_load_dword %0, %1, off sc0 sc1\n\t"
                             "s_waitcnt vmcnt(0)"
                             : "=v"(v) : "v"(p) : "memory");
            ok = __all(v >= target);
            if (!ok) __builtin_amdgcn_s_sleep(1);
        } while (!ok);
    }
    __syncthreads();
}

// ---------------------------------------------------------------------------
struct WChunk { f16x8 w0, w1; };

__device__ __forceinline__ WChunk loadW(int kt, const f16* __restrict__ W0,
                                        const f16* __restrict__ W1,
                                        int n0, int srow, int sch)
{
    const f16* Wp = (kt < 8) ? W0 : W1;
    const int  ko = ((kt < 8) ? kt : kt - 8) * 64;
    const f16* wp = Wp + (size_t)(n0 + srow) * H + ko + sch * 16;
    WChunk c;
    c.w0 = *(const f16x8*)wp;
    c.w1 = *(const f16x8*)(wp + 8);
    return c;
}

// Fused LSTM cell tile, 64 b-rows x 64 n', K = NKT*64 (NKT = 0, 8 or 16).
// A (h state) prefetched to regs via LLC loads; W via cached loads
// (L2-resident under the nt->XCD map). h output staged through LDS and
// written as coalesced 16B sc0sc1 stores (128 stores/block).
// xmode: 0 none; 1 enc0 F=8 fp32 x-path; 2 scalar xptr[b*xstride]; 3 pred_s.
template<int NKT>
__device__ __forceinline__ void cell_body(int bt, int nt, char* smem,
    const f16* __restrict__ A0, const f16* __restrict__ A1,
    const f16* __restrict__ W0, const f16* __restrict__ W1,
    const float* __restrict__ bih, const float* __restrict__ bhh,
    int xmode, const float* __restrict__ xptr, int xstride,
    const float* __restrict__ xw, const float* __restrict__ pred_s,
    float* __restrict__ cst, f16* __restrict__ hout)
{
    constexpr int ABUF = 64 * 72;                  // halfs per buffer slot
    f16*   As = (f16*)smem;                        // [2][64][72]
    f16*   Ws = (f16*)smem + 2 * ABUF;             // [2][64][72]
    float* zs = (float*)smem;                      // overlay after K-loop [64][68]
    f16*   hstage = (f16*)(smem + 20480);          // [64][16] f16 (2KB)

    const int tid  = threadIdx.x;
    const int lane = tid & 63;
    const int wv   = tid >> 6;
    const int wm   = wv & 1;
    const int wn   = wv >> 1;
    const int r    = lane & 15;
    const int g4   = lane >> 4;
    const int b0   = bt * 64;
    const int n0   = nt * 64;
    const int jh0  = nt * 16;
    const int srow = tid >> 2, sch = tid & 3;

    f32x4 acc[2][2] = {};

    if constexpr (NKT > 0) {
        f16x8 ar[16];
        f16x8 br[16];
        const f16* ap = A0 + (size_t)(b0 + srow) * H + sch * 16;
        LLC_LOAD16S(ap, ar);
        if constexpr (NKT == 16) {
            const f16* bp = A1 + (size_t)(b0 + srow) * H + sch * 16;
            LLC_LOAD16S(bp, br);
        }
        VWAIT16(ar);

        WChunk wcur = loadW(0, W0, W1, n0, srow, sch);
        #pragma unroll
        for (int kt = 0; kt < NKT; ++kt) {
            if (kt == 8) VWAIT16(br);
            f16* Ab = As + (kt & 1) * ABUF;
            f16* Wb = Ws + (kt & 1) * ABUF;
            f16x8 a0v = (kt < 8) ? ar[kt * 2]     : br[(kt - 8) * 2];
            f16x8 a1v = (kt < 8) ? ar[kt * 2 + 1] : br[(kt - 8) * 2 + 1];
            *(f16x8*)(Ab + srow * 72 + sch * 16)     = a0v;
            *(f16x8*)(Ab + srow * 72 + sch * 16 + 8) = a1v;
            *(f16x8*)(Wb + srow * 72 + sch * 16)     = wcur.w0;
            *(f16x8*)(Wb + srow * 72 + sch * 16 + 8) = wcur.w1;
            __syncthreads();

            WChunk wnxt = wcur;
            if (kt + 1 < NKT) wnxt = loadW(kt + 1, W0, W1, n0, srow, sch);

            #pragma unroll
            for (int sub = 0; sub < 2; ++sub) {
                f16x8 bf0 = *(const f16x8*)(Wb + (wn * 32 + r)      * 72 + sub * 32 + g4 * 8);
                f16x8 bf1 = *(const f16x8*)(Wb + (wn * 32 + 16 + r) * 72 + sub * 32 + g4 * 8);
                f16x8 af0 = *(const f16x8*)(Ab + (wm * 32 + r)      * 72 + sub * 32 + g4 * 8);
                f16x8 af1 = *(const f16x8*)(Ab + (wm * 32 + 16 + r) * 72 + sub * 32 + g4 * 8);
                acc[0][0] = __builtin_amdgcn_mfma_f32_16x16x32_f16(af0, bf0, acc[0][0], 0, 0, 0);
                acc[0][1] = __builtin_amdgcn_mfma_f32_16x16x32_f16(af0, bf1, acc[0][1], 0, 0, 0);
                acc[1][0] = __builtin_amdgcn_mfma_f32_16x16x32_f16(af1, bf0, acc[1][0], 0, 0, 0);
                acc[1][1] = __builtin_amdgcn_mfma_f32_16x16x32_f16(af1, bf1, acc[1][1], 0, 0, 0);
            }
            wcur = wnxt;
        }
    }

    __syncthreads();   // last frag reads drained before zs overlay
    #pragma unroll
    for (int fm = 0; fm < 2; ++fm)
        #pragma unroll
        for (int fn = 0; fn < 2; ++fn)
            #pragma unroll
            for (int j = 0; j < 4; ++j)
                zs[(wm * 32 + fm * 16 + g4 * 4 + j) * 68 +
                   (wn * 32 + fn * 16 + r)] = acc[fm][fn][j];
    __syncthreads();

    // epilogue: thread -> (4 b-rows, 1 jh); gates = 4 consecutive n'.
    const int jl = tid & 15;
    const int bq = tid >> 4;
    const int jh = jh0 + jl;

    float bsum[4];
    #pragma unroll
    for (int g = 0; g < 4; ++g) bsum[g] = bih[g * H + jh] + bhh[g * H + jh];

    #pragma unroll
    for (int bb = 0; bb < 4; ++bb) {
        const int bl = bq * 4 + bb;
        const int b  = b0 + bl;
        float4 z = *(const float4*)(zs + bl * 68 + jl * 4);
        float zi = z.x + bsum[0];
        float zf = z.y + bsum[1];
        float zg = z.z + bsum[2];
        float zo = z.w + bsum[3];
        if (xmode == 1) {
            const float* xr = xptr + (size_t)b * xstride;
            #pragma unroll
            for (int k = 0; k < F; ++k) {
                float xv = xr[k];
                zi += xv * xw[(0 * H + jh) * F + k];
                zf += xv * xw[(1 * H + jh) * F + k];
                zg += xv * xw[(2 * H + jh) * F + k];
                zo += xv * xw[(3 * H + jh) * F + k];
            }
        } else if (xmode == 2 || xmode == 3) {
            float xv = (xmode == 2) ? xptr[(size_t)b * xstride] : pred_s[bl];
            zi += xv * xw[0 * H + jh];
            zf += xv * xw[1 * H + jh];
            zg += xv * xw[2 * H + jh];
            zo += xv * xw[3 * H + jh];
        }
        size_t idx = (size_t)b * H + jh;
        float cold = cst[idx];                      // c is block-private: cached path
        float cn = sigm(zf) * cold + sigm(zi) * tanhf(zg);
        cst[idx] = cn;
        hstage[bl * 16 + jl] = (f16)(sigm(zo) * tanhf(cn));
    }
    __syncthreads();
    if (tid < 128) {                                // coalesced 16B h stores
        const int row = tid >> 1, half = tid & 1;
        f16x8 hv = *(const f16x8*)(hstage + row * 16 + half * 8);
        f16* hp = hout + (size_t)(b0 + row) * H + jh0 + half * 8;
        LLC_STORE_DWX4(hp, hv);
    }
}

// ---------------------------------------------------------------------------
// pred for 64 rows of this bt from h1d (prev kernel -> cached reads OK).
// All 32 nt blocks compute redundantly; nt==0 writes d_out[., oidx].
__device__ __forceinline__ void compute_pred(int bt, int nt,
                             const f16* __restrict__ h1src,
                             const float* __restrict__ outW,
                             const float* __restrict__ outb,
                             float* pred_s, float* __restrict__ dout, int oidx)
{
    const int row = threadIdx.x >> 2;
    const int q   = threadIdx.x & 3;
    const int b   = bt * 64 + row;
    const f16x8* hv = (const f16x8*)(h1src + (size_t)b * H + q * 128);
    float s = 0.f;
    #pragma unroll
    for (int k8 = 0; k8 < 16; ++k8) {
        f16x8 h8 = hv[k8];
        const float* wr = outW + q * 128 + k8 * 8;
        #pragma unroll
        for (int j = 0; j < 8; ++j) s += (float)h8[j] * wr[j];
    }
    s += __shfl_down(s, 2);
    s += __shfl_down(s, 1);
    if (q == 0) {
        float p = s + outb[0];
        pred_s[row] = p;
        if (nt == 0) dout[(size_t)b * HOR + oidx] = p;
    }
    __syncthreads();
}

// ---------------------------------------------------------------------------
struct PArgs {
    const f16 *wh0, *wih1, *whh1, *dwh0, *dwih1, *dwhh1;
    const float *x;
    const float *ebih0, *ebhh0, *ebih1, *ebhh1;
    const float *dbih0, *dbhh0, *dbih1, *dbhh1;
    const float *eWih0, *dWih0, *outW, *outb;
    f16 *h0ring, *h1ping, *h0dping, *h1dping;
    float *c0, *c1, *dout;
    int *f0, *f1;                     // epoch flags, [8 bt][32 nt] each
};

// Encoder 2-step kernel, slot s covers t0=2s (layer0), t1=2s+1 (layer0) and
// l1(2s-1), l1(2s) (layer1). Grid 512 (all co-resident: 37.1KB LDS, <=256
// VGPR -> >=2 blocks/CU). bid bits: [2:0]=nt&7 (XCD), [3]=role, [6:4]=bt,
// [8:7]=nt>>3. Cross-slot deps ride kernel boundaries (HW coherence); the
// two intra-kernel handoffs use the R6/R7-proven sc0sc1 flag path.
__global__ __launch_bounds__(256, 2)
void enc2_k(PArgs a, int s)
{
    __shared__ __align__(16) char smem[37120];
    const size_t BH = (size_t)B * H;
    const int bid  = blockIdx.x;
    const int role = (bid >> 3) & 1;
    const int bt   = (bid >> 4) & 7;
    const int nt   = (bid & 7) | ((bid >> 7) << 3);
    int* const myf0 = a.f0 + bt * 32;
    int* const myf1 = a.f1 + bt * 32;
    const int t0 = 2 * s, t1 = 2 * s + 1;

    if (role == 0) {
        // layer0 step t0 (deps: prev kernel only)
        const f16* hp = a.h0ring + (size_t)((t0 + 3) & 3) * BH;
        f16* ho = a.h0ring + (size_t)(t0 & 3) * BH;
        if (t0 == 0)
            cell_body<0>(bt, nt, smem, hp, hp, a.wh0, a.wh0, a.ebih0, a.ebhh0,
                         1, a.x + (size_t)t0 * F, T * F, a.eWih0, nullptr, a.c0, ho);
        else
            cell_body<8>(bt, nt, smem, hp, hp, a.wh0, a.wh0, a.ebih0, a.ebhh0,
                         1, a.x + (size_t)t0 * F, T * F, a.eWih0, nullptr, a.c0, ho);
        __syncthreads();
        if (threadIdx.x == 0) FLAG_STORE(myf0 + nt, t0 + 1);
        // self-group barrier: full h0(t0) visible
        wait_group(myf0, t0 + 1);
        // layer0 step t1
        cell_body<8>(bt, nt, smem, ho, ho, a.wh0, a.wh0, a.ebih0, a.ebhh0,
                     1, a.x + (size_t)t1 * F, T * F, a.eWih0, nullptr, a.c0,
                     a.h0ring + (size_t)(t1 & 3) * BH);
        // no end flag: kernel boundary releases h0(t1)
    } else {
        // layer1 step ta = 2s-1 (deps: prev kernel only), skip at s==0
        if (s > 0) {
            const int ta = 2 * s - 1;
            cell_body<16>(bt, nt, smem,
                          a.h0ring + (size_t)(ta & 3) * BH,
                          a.h1ping + (size_t)((ta + 1) & 1) * BH,
                          a.wih1, a.whh1, a.ebih1, a.ebhh1,
                          0, nullptr, 0, nullptr, nullptr,
                          a.c1, a.h1ping + (size_t)(ta & 1) * BH);
            __syncthreads();
            if (threadIdx.x == 0) FLAG_STORE(myf1 + nt, ta + 1);
        }
        // layer1 step tb = 2s (needs h0(2s) intra + h1(2s-1) intra)
        const int tb = 2 * s;
        wait_group(myf0, tb + 1);
        if (s > 0) wait_group(myf1, tb);
        const f16* a0 = a.h0ring + (size_t)(tb & 3) * BH;
        f16* ho = a.h1ping + (size_t)(tb & 1) * BH;
        if (tb == 0)
            cell_body<8>(bt, nt, smem, a0, a0, a.wih1, a.wih1, a.ebih1, a.ebhh1,
                         0, nullptr, 0, nullptr, nullptr, a.c1, ho);
        else
            cell_body<16>(bt, nt, smem, a0,
                          a.h1ping + (size_t)((tb + 1) & 1) * BH,
                          a.wih1, a.whh1, a.ebih1, a.ebhh1,
                          0, nullptr, 0, nullptr, nullptr, a.c1, ho);
    }
}

// Encoder tail: l1(255) only (all deps prev kernel). Grid 256.
__global__ __launch_bounds__(256, 2)
void enctail_k(PArgs a)
{
    __shared__ __align__(16) char smem[37120];
    const size_t BH = (size_t)B * H;
    const int bid = blockIdx.x;
    const int bt  = (bid >> 3) & 7;
    const int nt  = (bid & 7) | ((bid >> 6) << 3);
    cell_body<16>(bt, nt, smem,
                  a.h0ring + (size_t)3 * BH,           // h0(255)
                  a.h1ping,                            // h1(254) slot 0
                  a.wih1, a.whh1, a.ebih1, a.ebhh1,
                  0, nullptr, 0, nullptr, nullptr,
                  a.c1, a.h1ping + BH);                // h1(255) -> slot 1
}

// Decoder layer0 (+ inline pred head). Grid 256, no flags (boundary deps).
__global__ __launch_bounds__(256, 2)
void dec0_k(PArgs a, int td)
{
    __shared__ __align__(16) char smem[37120];
    float* pred_s = (float*)(smem + 36864);
    const size_t BH = (size_t)B * H;
    const int bid = blockIdx.x;
    const int bt  = (bid >> 3) & 7;
    const int nt  = (bid & 7) | ((bid >> 6) << 3);

    if (td == 0) {
        const f16* hp = a.h0ring + (size_t)3 * BH;     // h0(255)
        cell_body<8>(bt, nt, smem, hp, hp, a.dwh0, a.dwh0, a.dbih0, a.dbhh0,
                     2, a.x + (size_t)(T - 1) * F, T * F, a.dWih0, nullptr,
                     a.c0, a.h0dping);
    } else {
        compute_pred(bt, nt, a.h1dping + (size_t)((td + 1) & 1) * BH,
                     a.outW, a.outb, pred_s, a.dout, td - 1);
        const f16* hp = a.h0dping + (size_t)((td + 1) & 1) * BH;
        cell_body<8>(bt, nt, smem, hp, hp, a.dwh0, a.dwh0, a.dbih0, a.dbhh0,
                     3, nullptr, 0, a.dWih0, pred_s,
                     a.c0, a.h0dping + (size_t)(td & 1) * BH);
    }
}

// Decoder layer1. Grid 256, no flags (boundary deps).
__global__ __launch_bounds__(256, 2)
void dec1_k(PArgs a, int td)
{
    __shared__ __align__(16) char smem[37120];
    const size_t BH = (size_t)B * H;
    const int bid = blockIdx.x;
    const int bt  = (bid >> 3) & 7;
    const int nt  = (bid & 7) | ((bid >> 6) << 3);
    const f16* a1 = (td == 0) ? a.h1ping + BH
                              : a.h1dping + (size_t)((td + 1) & 1) * BH;
    cell_body<16>(bt, nt, smem, a.h0dping + (size_t)(td & 1) * BH, a1,
                  a.dwih1, a.dwhh1, a.dbih1, a.dbhh1,
                  0, nullptr, 0, nullptr, nullptr,
                  a.c1, a.h1dping + (size_t)(td & 1) * BH);
}

// Final pred (td = HOR-1). Grid 128 x 256.
__global__ __launch_bounds__(256)
void predf_k(const f16* __restrict__ h1, const float* __restrict__ outW,
             const float* __restrict__ outb, float* __restrict__ dout)
{
    int wv = threadIdx.x >> 6, lane = threadIdx.x & 63;
    int b = blockIdx.x * 4 + wv;
    const f16* hr = h1 + (size_t)b * H;
    float s = 0.f;
    #pragma unroll
    for (int k = 0; k < H; k += 64) s += (float)hr[k + lane] * outW[k + lane];
    #pragma unroll
    for (int off = 32; off > 0; off >>= 1) s += __shfl_down(s, off);
    if (lane == 0) dout[(size_t)b * HOR + (HOR - 1)] = s + outb[0];
}

// ---------------------------------------------------------------------------
extern "C" void kernel_launch(void* const* d_in, const int* in_sizes, int n_in,
                              void* d_out, int out_size, void* d_ws, size_t ws_size,
                              hipStream_t stream)
{
    const float* x     = (const float*)d_in[0];
    const float* eWih0 = (const float*)d_in[1];
    const float* eWhh0 = (const float*)d_in[2];
    const float* ebih0 = (const float*)d_in[3];
    const float* ebhh0 = (const float*)d_in[4];
    const float* eWih1 = (const float*)d_in[5];
    const float* eWhh1 = (const float*)d_in[6];
    const float* ebih1 = (const float*)d_in[7];
    const float* ebhh1 = (const float*)d_in[8];
    const float* dWih0 = (const float*)d_in[9];
    const float* dWhh0 = (const float*)d_in[10];
    const float* dbih0 = (const float*)d_in[11];
    const float* dbhh0 = (const float*)d_in[12];
    const float* dWih1 = (const float*)d_in[13];
    const float* dWhh1 = (const float*)d_in[14];
    const float* dbih1 = (const float*)d_in[15];
    const float* dbhh1 = (const float*)d_in[16];
    const float* outW  = (const float*)d_in[17];
    const float* outb  = (const float*)d_in[18];

    const size_t WSZ = (size_t)4 * H * H;   // halfs per converted weight
    const size_t BH  = (size_t)B * H;

    char* wsb = (char*)d_ws;
    size_t off = 0;
    f16* wh[6];
    for (int i = 0; i < 6; ++i) { wh[i] = (f16*)(wsb + off); off += WSZ * sizeof(f16); }
    f16* h0ring  = (f16*)(wsb + off); off += 4 * BH * sizeof(f16);
    f16* h1ping  = (f16*)(wsb + off); off += 2 * BH * sizeof(f16);
    f16* h0dping = (f16*)(wsb + off); off += 2 * BH * sizeof(f16);
    f16* h1dping = (f16*)(wsb + off); off += 2 * BH * sizeof(f16);
    float* c0    = (float*)(wsb + off); off += BH * sizeof(float);
    float* c1    = (float*)(wsb + off); off += BH * sizeof(float);
    size_t coff  = off;
    int* f0      = (int*)(wsb + off); off += 8 * 32 * sizeof(int);
    int* f1      = (int*)(wsb + off); off += 8 * 32 * sizeof(int);
    size_t cbytes = off - coff;

    // fp16 weight conversion (permuted layout) + state/flag init, every call
    wconv_k<<<dim3(512, 6), 256, 0, stream>>>(eWhh0, wh[0], eWih1, wh[1], eWhh1, wh[2],
                                              dWhh0, wh[3], dWih1, wh[4], dWhh1, wh[5]);
    hipMemsetAsync(c0, 0, BH * sizeof(float), stream);
    hipMemsetAsync(c1, 0, BH * sizeof(float), stream);
    hipMemsetAsync((char*)wsb + coff, 0, cbytes, stream);

    PArgs a;
    a.wh0 = wh[0]; a.wih1 = wh[1]; a.whh1 = wh[2];
    a.dwh0 = wh[3]; a.dwih1 = wh[4]; a.dwhh1 = wh[5];
    a.x = x;
    a.ebih0 = ebih0; a.ebhh0 = ebhh0; a.ebih1 = ebih1; a.ebhh1 = ebhh1;
    a.dbih0 = dbih0; a.dbhh0 = dbhh0; a.dbih1 = dbih1; a.dbhh1 = dbhh1;
    a.eWih0 = eWih0; a.dWih0 = dWih0; a.outW = outW; a.outb = outb;
    a.h0ring = h0ring; a.h1ping = h1ping; a.h0dping = h0dping; a.h1dping = h1dping;
    a.c0 = c0; a.c1 = c1; a.dout = (float*)d_out;
    a.f0 = f0; a.f1 = f1;

    // encoder: 128 two-step slots + layer1 tail
    for (int s = 0; s < T / 2; ++s)
        enc2_k<<<dim3(512), dim3(256), 0, stream>>>(a, s);
    enctail_k<<<dim3(256), dim3(256), 0, stream>>>(a);

    // decoder: 2 kernels/step, pred fused into next dec0; final pred kernel
    for (int td = 0; td < HOR; ++td) {
        dec0_k<<<dim3(256), dim3(256), 0, stream>>>(a, td);
        dec1_k<<<dim3(256), dim3(256), 0, stream>>>(a, td);
    }
    predf_k<<<dim3(128), dim3(256), 0, stream>>>(h1dping + BH, outW, outb, (float*)d_out);
}